// Round 2
// baseline (7224.077 us; speedup 1.0000x reference)
//
#include <hip/hip_runtime.h>

typedef unsigned short u16;
typedef short bfx8 __attribute__((ext_vector_type(8)));
typedef float fx4 __attribute__((ext_vector_type(4)));

__device__ __forceinline__ float b2f(u16 u) {
    union { unsigned u; float f; } c; c.u = ((unsigned)u) << 16; return c.f;
}
__device__ __forceinline__ u16 f2b(float f) {
    union { float f; unsigned u; } c; c.f = f;
    unsigned x = c.u;
    unsigned r = x + 0x7FFFu + ((x >> 16) & 1u);
    return (u16)(r >> 16);
}

// ---------------- f32 -> bf16 cast (8 elems/thread) ----------------
__global__ void k_cast(const float* __restrict__ xf, u16* __restrict__ xb, int n8) {
    int t = blockIdx.x * 256 + threadIdx.x;
    if (t >= n8) return;
    const float4* p = (const float4*)xf;
    float4 a = p[t * 2], b = p[t * 2 + 1];
    u16 o[8];
    o[0] = f2b(a.x); o[1] = f2b(a.y); o[2] = f2b(a.z); o[3] = f2b(a.w);
    o[4] = f2b(b.x); o[5] = f2b(b.y); o[6] = f2b(b.z); o[7] = f2b(b.w);
    ((uint4*)xb)[t] = *(uint4*)o;
}

// ---------------- CSR build ----------------

__global__ void k_deg(const int* __restrict__ dst, int* __restrict__ rp, int E) {
    int e = blockIdx.x * 256 + threadIdx.x;
    if (e < E) atomicAdd(&rp[dst[e]], 1);
}

#define SCAN_T 256
#define SCAN_I 8
#define SCAN_CH 2048

__global__ void k_scanA(int* __restrict__ rp, int* __restrict__ bsum, int N) {
    __shared__ int s[SCAN_T];
    int base = blockIdx.x * SCAN_CH + threadIdx.x * SCAN_I;
    int v[SCAN_I]; int tot = 0;
    for (int i = 0; i < SCAN_I; i++) {
        int idx = base + i;
        int x = (idx < N) ? rp[idx] : 0;
        v[i] = tot; tot += x;
    }
    s[threadIdx.x] = tot; __syncthreads();
    for (int off = 1; off < SCAN_T; off <<= 1) {
        int t = (threadIdx.x >= off) ? s[threadIdx.x - off] : 0;
        __syncthreads();
        s[threadIdx.x] += t;
        __syncthreads();
    }
    int excl = (threadIdx.x == 0) ? 0 : s[threadIdx.x - 1];
    if (threadIdx.x == SCAN_T - 1) bsum[blockIdx.x] = s[SCAN_T - 1];
    for (int i = 0; i < SCAN_I; i++) {
        int idx = base + i;
        if (idx < N) rp[idx] = excl + v[i];
    }
}

__global__ void k_scanB(int* __restrict__ bsum, int nb) {
    __shared__ int s[SCAN_T];
    int t = threadIdx.x;
    s[t] = (t < nb) ? bsum[t] : 0; __syncthreads();
    for (int off = 1; off < SCAN_T; off <<= 1) {
        int v = (t >= off) ? s[t - off] : 0;
        __syncthreads();
        s[t] += v;
        __syncthreads();
    }
    if (t < nb) bsum[t] = (t == 0) ? 0 : s[t - 1];
}

__global__ void k_scanC(const int* __restrict__ bsum, int* __restrict__ rp,
                        int* __restrict__ cursor, int N, int E) {
    int i = blockIdx.x * 256 + threadIdx.x;
    if (i < N) {
        int v = rp[i] + bsum[i >> 11];
        rp[i] = v; cursor[i] = v;
    } else if (i == N) {
        rp[N] = E;
    }
}

__global__ void k_fill(const int* __restrict__ src, const int* __restrict__ dst,
                       int* __restrict__ cursor, int* __restrict__ col_src,
                       int* __restrict__ col_eid, int E) {
    int e = blockIdx.x * 256 + threadIdx.x;
    if (e >= E) return;
    int d = dst[e];
    int p = atomicAdd(&cursor[d], 1);
    col_src[p] = src[e];
    col_eid[p] = e;
}

__global__ void k_gptr(const int* __restrict__ batch, int* __restrict__ gptr, int N, int G) {
    int g = blockIdx.x * 256 + threadIdx.x;
    if (g > G) return;
    int lo = 0, hi = N;
    while (lo < hi) { int mid = (lo + hi) >> 1; if (batch[mid] < g) lo = mid + 1; else hi = mid; }
    gptr[g] = lo;
}

// agg_e[n][m] = sum of edge_attr (f32) over in-edges of n (constant across convs)
__global__ void k_agge(const float* __restrict__ ea, const int* __restrict__ rp,
                       const int* __restrict__ col_eid, float* __restrict__ agge, int N) {
    int t = blockIdx.x * 256 + threadIdx.x;
    int n = t >> 4, m = t & 15;
    if (n >= N) return;
    float v = 0.f;
    int p1 = rp[n + 1];
    for (int p = rp[n]; p < p1; p++) v += ea[(size_t)col_eid[p] * 16 + m];
    agge[(size_t)n * 16 + m] = v;
}

// ---------------- fused softmax + segment-sum pool (MFMA) ----------------
// wave per graph; W_out (f32) staged in LDS as bf16, pre-swizzled into B-fragment order.
__global__ __launch_bounds__(256, 2) void k_pass(
    const u16* __restrict__ x, const float* __restrict__ Wow, const float* __restrict__ Wob,
    const int* __restrict__ gptr, float* __restrict__ fp, int G, int writeMode)
{
    __shared__ u16 Wsw[64 * 64 * 8];   // [64 frags][64 lanes][8 bf16] = 64 KB
    for (int s = threadIdx.x; s < 4096; s += 256) {
        int frag = s >> 6, lane = s & 63;
        int ft = frag >> 1, kt = frag & 1;
        int f = ft * 16 + (lane & 15);
        int k = kt * 32 + ((lane >> 4) & 3) * 8;
        const float* wp = Wow + f * 64 + k;      // B[k][f] = W_out[f][k], 8 consecutive k
        u16 o[8];
#pragma unroll
        for (int i = 0; i < 8; i++) o[i] = f2b(wp[i]);
        ((uint4*)Wsw)[s] = *(uint4*)o;
    }
    __syncthreads();
    const int wid = threadIdx.x >> 6, lane = threadIdx.x & 63;
    const int quad = lane >> 4, col = lane & 15;
    for (int g = blockIdx.x * 4 + wid; g < G; g += gridDim.x * 4) {
        int gs = gptr[g], ge = gptr[g + 1];
        int cnt = ge - gs;
        float fpacc[32];
#pragma unroll
        for (int t = 0; t < 32; t++) fpacc[t] = 0.f;
        int ntiles = (cnt + 15) >> 4;
        for (int nt = 0; nt < ntiles; nt++) {
            int node = gs + nt * 16 + col;           // A-layout: m = lane&15
            bool valid = node < ge;
            const uint4* rowp = (const uint4*)(x + (size_t)(valid ? node : gs) * 64);
            uint4 a0u = rowp[quad];
            uint4 a1u = rowp[quad + 4];
            if (!valid) { a0u.x = a0u.y = a0u.z = a0u.w = 0u; a1u = a0u; }
            bfx8 a0 = *(bfx8*)&a0u;
            bfx8 a1 = *(bfx8*)&a1u;
            fx4 z[32];
#pragma unroll
            for (int ft = 0; ft < 32; ft++) {
                float b = Wob[ft * 16 + col];
                fx4 acc = {b, b, b, b};
                bfx8 b0 = *(bfx8*)(Wsw + ((ft * 2 + 0) * 64 + lane) * 8);
                bfx8 b1 = *(bfx8*)(Wsw + ((ft * 2 + 1) * 64 + lane) * 8);
                acc = __builtin_amdgcn_mfma_f32_16x16x32_bf16(a0, b0, acc, 0, 0, 0);
                acc = __builtin_amdgcn_mfma_f32_16x16x32_bf16(a1, b1, acc, 0, 0, 0);
                z[ft] = acc;
            }
            // per-row (node) max over all 512 features: regs + 16-lane (quad) shuffle
            float sc[4];
#pragma unroll
            for (int r = 0; r < 4; r++) {
                float mm = z[0][r];
#pragma unroll
                for (int ft = 1; ft < 32; ft++) mm = fmaxf(mm, z[ft][r]);
#pragma unroll
                for (int off = 1; off < 16; off <<= 1) mm = fmaxf(mm, __shfl_xor(mm, off, 64));
                sc[r] = mm;
            }
            float sum[4] = {0.f, 0.f, 0.f, 0.f};
#pragma unroll
            for (int ft = 0; ft < 32; ft++) {
#pragma unroll
                for (int r = 0; r < 4; r++) {
                    float e = __expf(z[ft][r] - sc[r]);
                    z[ft][r] = e;
                    sum[r] += e;
                }
            }
            int rowbase = nt * 16 + quad * 4;        // C-layout: row = quad*4+reg
#pragma unroll
            for (int r = 0; r < 4; r++) {
                float ss = sum[r];
#pragma unroll
                for (int off = 1; off < 16; off <<= 1) ss += __shfl_xor(ss, off, 64);
                sc[r] = (rowbase + r < cnt) ? (1.0f / ss) : 0.f;   // mask pad rows
            }
#pragma unroll
            for (int ft = 0; ft < 32; ft++)
                fpacc[ft] += z[ft][0] * sc[0] + z[ft][1] * sc[1] + z[ft][2] * sc[2] + z[ft][3] * sc[3];
        }
#pragma unroll
        for (int ft = 0; ft < 32; ft++) {
            float v = fpacc[ft];
            v += __shfl_xor(v, 16, 64);
            v += __shfl_xor(v, 32, 64);
            if (lane < 16) {
                float* dp = fp + (size_t)g * 512 + ft * 16 + col;
                if (writeMode) *dp = v; else *dp += v;
            }
        }
    }
}

// ---------------- conv part 1: y = x @ W1.T (MFMA, N x 64 x 64) ----------------
__global__ __launch_bounds__(256) void k_gemm(
    const u16* __restrict__ x, const float* __restrict__ Wiw, u16* __restrict__ y, int N)
{
    __shared__ u16 Wsw[8 * 64 * 8];
    for (int s = threadIdx.x; s < 512; s += 256) {
        int frag = s >> 6, lane = s & 63;
        int ft = frag >> 1, kt = frag & 1;
        int f = ft * 16 + (lane & 15);
        int k = kt * 32 + ((lane >> 4) & 3) * 8;
        const float* wp = Wiw + f * 80 + k;      // W1[f][k] = W_in_w[f*80 + k]
        u16 o[8];
#pragma unroll
        for (int i = 0; i < 8; i++) o[i] = f2b(wp[i]);
        ((uint4*)Wsw)[s] = *(uint4*)o;
    }
    __syncthreads();
    const int wid = threadIdx.x >> 6, lane = threadIdx.x & 63;
    const int quad = lane >> 4, col = lane & 15;
    int ntile = N >> 4;
    for (int t = blockIdx.x * 4 + wid; t < ntile; t += gridDim.x * 4) {
        const uint4* rowp = (const uint4*)(x + (size_t)(t * 16 + col) * 64);
        uint4 a0u = rowp[quad], a1u = rowp[quad + 4];
        bfx8 a0 = *(bfx8*)&a0u, a1 = *(bfx8*)&a1u;
#pragma unroll
        for (int ft = 0; ft < 4; ft++) {
            fx4 acc = {0.f, 0.f, 0.f, 0.f};
            bfx8 b0 = *(bfx8*)(Wsw + ((ft * 2 + 0) * 64 + lane) * 8);
            bfx8 b1 = *(bfx8*)(Wsw + ((ft * 2 + 1) * 64 + lane) * 8);
            acc = __builtin_amdgcn_mfma_f32_16x16x32_bf16(a0, b0, acc, 0, 0, 0);
            acc = __builtin_amdgcn_mfma_f32_16x16x32_bf16(a1, b1, acc, 0, 0, 0);
#pragma unroll
            for (int r = 0; r < 4; r++)
                y[(size_t)(t * 16 + quad * 4 + r) * 64 + ft * 16 + col] = f2b(acc[r]);
        }
    }
}

// ---------------- conv part 2: x_out[n] = y[n] + sum_{e->n} y[src] + agg_e[n]@W2.T + b ----------------
__global__ __launch_bounds__(256) void k_gath(
    const u16* __restrict__ y, const float* __restrict__ agge,
    const float* __restrict__ Wiw, const float* __restrict__ Wib,
    const int* __restrict__ rp, const int* __restrict__ col_src,
    u16* __restrict__ xb, int N)
{
    __shared__ float W2t[16 * 64];
    __shared__ float bias[64];
    for (int s = threadIdx.x; s < 1024; s += 256) {
        int m = s >> 6, j = s & 63;
        W2t[s] = Wiw[j * 80 + 64 + m];
    }
    if (threadIdx.x < 64) bias[threadIdx.x] = Wib[threadIdx.x];
    __syncthreads();
    const int wid = threadIdx.x >> 6, lane = threadIdx.x & 63;
    int nw = gridDim.x * 4;
    for (int n = blockIdx.x * 4 + wid; n < N; n += nw) {
        float acc = b2f(y[(size_t)n * 64 + lane]) + bias[lane];   // self loop + bias
        int p1 = rp[n + 1];
        for (int p = rp[n]; p < p1; p++) {
            int s = col_src[p];
            acc += b2f(y[(size_t)s * 64 + lane]);
        }
        const float* ae = agge + (size_t)n * 16;
#pragma unroll
        for (int m = 0; m < 16; m++) acc += ae[m] * W2t[m * 64 + lane];
        xb[(size_t)n * 64 + lane] = f2b(acc);
    }
}

// ---------------- head: sigmoid(lin2(lin1(fp))) — all f32 ----------------
__global__ __launch_bounds__(256) void k_head(
    const float* __restrict__ fp, const float* __restrict__ l1w, const float* __restrict__ l1b,
    const float* __restrict__ l2w, const float* __restrict__ l2b, float* __restrict__ out, int G)
{
    const int wid = threadIdx.x >> 6, lane = threadIdx.x & 63;
    int g = blockIdx.x * 4 + wid;
    if (g >= G) return;
    int j = lane < 50 ? lane : 49;
    float h = 0.f;
    const float4* fv = (const float4*)(fp + (size_t)g * 512);
    const float4* wv = (const float4*)(l1w + (size_t)j * 512);
    for (int q = 0; q < 128; q++) {
        float4 w = wv[q], f = fv[q];
        h += w.x * f.x + w.y * f.y + w.z * f.z + w.w * f.w;
    }
    h += l1b[j];
    float val = (lane < 50) ? h * l2w[lane] : 0.f;
#pragma unroll
    for (int off = 1; off < 64; off <<= 1) val += __shfl_xor(val, off, 64);
    if (lane == 0) {
        float o = val + l2b[0];
        out[g] = 1.f / (1.f + __expf(-o));
    }
}

extern "C" void kernel_launch(void* const* d_in, const int* in_sizes, int n_in,
                              void* d_out, int out_size, void* d_ws, size_t ws_size,
                              hipStream_t stream)
{
    const float* x    = (const float*)d_in[0];
    const float* ea   = (const float*)d_in[1];
    const float* Wiw  = (const float*)d_in[2];
    const float* Wib  = (const float*)d_in[3];
    const float* Wow  = (const float*)d_in[4];
    const float* Wob  = (const float*)d_in[5];
    const float* l1w  = (const float*)d_in[6];
    const float* l1b  = (const float*)d_in[7];
    const float* l2w  = (const float*)d_in[8];
    const float* l2b  = (const float*)d_in[9];
    const int* ei     = (const int*)d_in[10];
    const int* batch  = (const int*)d_in[11];
    float* out = (float*)d_out;

    const int N = in_sizes[0] / 64;
    const int E = in_sizes[10] / 2;
    const int G = 16384;
    const int* src = ei;
    const int* dst = ei + E;

    size_t o = 0;
    auto give = [&](size_t bytes) {
        char* p = (char*)d_ws + o;
        o += (bytes + 255) & ~(size_t)255;
        return (void*)p;
    };
    u16*   x16     = (u16*)  give((size_t)N * 64 * 2);   // bf16 cast of input x
    u16*   xb      = (u16*)  give((size_t)N * 64 * 2);   // conv output (bf16)
    u16*   y       = (u16*)  give((size_t)N * 64 * 2);   // x @ W1.T  (bf16)
    float* agge    = (float*)give((size_t)N * 16 * 4);
    float* fp      = (float*)give((size_t)G * 512 * 4);
    int*   rp      = (int*)  give((size_t)(N + 1) * 4);
    int*   cursor  = (int*)  give((size_t)N * 4);
    int*   col_src = (int*)  give((size_t)E * 4);
    int*   col_eid = (int*)  give((size_t)E * 4);
    int*   bsum    = (int*)  give(4096);
    int*   gptr    = (int*)  give((size_t)(G + 1) * 4);

    // CSR build (inputs identical each call so result identical each launch)
    hipMemsetAsync(rp, 0, (size_t)(N + 1) * 4, stream);
    k_deg<<<(E + 255) / 256, 256, 0, stream>>>(dst, rp, E);
    int nb = (N + SCAN_CH - 1) / SCAN_CH;       // 245 for N=500000 (must be <= 256)
    k_scanA<<<nb, SCAN_T, 0, stream>>>(rp, bsum, N);
    k_scanB<<<1, SCAN_T, 0, stream>>>(bsum, nb);
    k_scanC<<<(N + 256) / 256, 256, 0, stream>>>(bsum, rp, cursor, N, E);
    k_fill<<<(E + 255) / 256, 256, 0, stream>>>(src, dst, cursor, col_src, col_eid, E);
    k_gptr<<<(G + 256) / 256, 256, 0, stream>>>(batch, gptr, N, G);
    k_agge<<<(N * 16 + 255) / 256, 256, 0, stream>>>(ea, rp, col_eid, agge, N);

    // cast input x -> bf16
    k_cast<<<(N * 64 / 8 + 255) / 256, 256, 0, stream>>>(x, x16, N * 64 / 8);

    // pass 0 on input x (writes fp)
    k_pass<<<512, 256, 0, stream>>>(x16, Wow, Wob, gptr, fp, G, 1);
    const u16* xc = x16;
    for (int d = 0; d < 4; d++) {
        k_gemm<<<1024, 256, 0, stream>>>(xc, Wiw, y, N);
        k_gath<<<2048, 256, 0, stream>>>(y, agge, Wiw, Wib, rp, col_src, xb, N);
        xc = xb;
        k_pass<<<512, 256, 0, stream>>>(xc, Wow, Wob, gptr, fp, G, 0);
    }
    k_head<<<G / 4, 256, 0, stream>>>(fp, l1w, l1b, l2w, l2b, out, G);
}

// Round 3
// 3938.186 us; speedup vs baseline: 1.8344x; 1.8344x over previous
//
#include <hip/hip_runtime.h>

typedef unsigned short u16;
typedef short bfx8 __attribute__((ext_vector_type(8)));
typedef float fx4 __attribute__((ext_vector_type(4)));

__device__ __forceinline__ float b2f(u16 u) {
    union { unsigned u; float f; } c; c.u = ((unsigned)u) << 16; return c.f;
}
__device__ __forceinline__ u16 f2b(float f) {
    union { float f; unsigned u; } c; c.f = f;
    unsigned x = c.u;
    unsigned r = x + 0x7FFFu + ((x >> 16) & 1u);
    return (u16)(r >> 16);
}
__device__ __forceinline__ float bpk_lo(unsigned p) {
    union { unsigned u; float f; } c; c.u = p << 16; return c.f;
}
__device__ __forceinline__ float bpk_hi(unsigned p) {
    union { unsigned u; float f; } c; c.u = p & 0xFFFF0000u; return c.f;
}

// ---------------- f32 -> bf16 cast (8 elems/thread) ----------------
__global__ void k_cast(const float* __restrict__ xf, u16* __restrict__ xb, int n8) {
    int t = blockIdx.x * 256 + threadIdx.x;
    if (t >= n8) return;
    const float4* p = (const float4*)xf;
    float4 a = p[t * 2], b = p[t * 2 + 1];
    u16 o[8];
    o[0] = f2b(a.x); o[1] = f2b(a.y); o[2] = f2b(a.z); o[3] = f2b(a.w);
    o[4] = f2b(b.x); o[5] = f2b(b.y); o[6] = f2b(b.z); o[7] = f2b(b.w);
    ((uint4*)xb)[t] = *(uint4*)o;
}

// ---------------- CSR build ----------------

__global__ void k_deg(const int* __restrict__ dst, int* __restrict__ rp, int E) {
    int e = blockIdx.x * 256 + threadIdx.x;
    if (e < E) atomicAdd(&rp[dst[e]], 1);
}

#define SCAN_T 256
#define SCAN_I 8
#define SCAN_CH 2048

__global__ void k_scanA(int* __restrict__ rp, int* __restrict__ bsum, int N) {
    __shared__ int s[SCAN_T];
    int base = blockIdx.x * SCAN_CH + threadIdx.x * SCAN_I;
    int v[SCAN_I]; int tot = 0;
    for (int i = 0; i < SCAN_I; i++) {
        int idx = base + i;
        int x = (idx < N) ? rp[idx] : 0;
        v[i] = tot; tot += x;
    }
    s[threadIdx.x] = tot; __syncthreads();
    for (int off = 1; off < SCAN_T; off <<= 1) {
        int t = (threadIdx.x >= off) ? s[threadIdx.x - off] : 0;
        __syncthreads();
        s[threadIdx.x] += t;
        __syncthreads();
    }
    int excl = (threadIdx.x == 0) ? 0 : s[threadIdx.x - 1];
    if (threadIdx.x == SCAN_T - 1) bsum[blockIdx.x] = s[SCAN_T - 1];
    for (int i = 0; i < SCAN_I; i++) {
        int idx = base + i;
        if (idx < N) rp[idx] = excl + v[i];
    }
}

__global__ void k_scanB(int* __restrict__ bsum, int nb) {
    __shared__ int s[SCAN_T];
    int t = threadIdx.x;
    s[t] = (t < nb) ? bsum[t] : 0; __syncthreads();
    for (int off = 1; off < SCAN_T; off <<= 1) {
        int v = (t >= off) ? s[t - off] : 0;
        __syncthreads();
        s[t] += v;
        __syncthreads();
    }
    if (t < nb) bsum[t] = (t == 0) ? 0 : s[t - 1];
}

__global__ void k_scanC(const int* __restrict__ bsum, int* __restrict__ rp,
                        int* __restrict__ cursor, int N, int E) {
    int i = blockIdx.x * 256 + threadIdx.x;
    if (i < N) {
        int v = rp[i] + bsum[i >> 11];
        rp[i] = v; cursor[i] = v;
    } else if (i == N) {
        rp[N] = E;
    }
}

__global__ void k_fill(const int* __restrict__ src, const int* __restrict__ dst,
                       int* __restrict__ cursor, int* __restrict__ col_src,
                       int* __restrict__ col_eid, int E) {
    int e = blockIdx.x * 256 + threadIdx.x;
    if (e >= E) return;
    int d = dst[e];
    int p = atomicAdd(&cursor[d], 1);
    col_src[p] = src[e];
    col_eid[p] = e;
}

__global__ void k_gptr(const int* __restrict__ batch, int* __restrict__ gptr, int N, int G) {
    int g = blockIdx.x * 256 + threadIdx.x;
    if (g > G) return;
    int lo = 0, hi = N;
    while (lo < hi) { int mid = (lo + hi) >> 1; if (batch[mid] < g) lo = mid + 1; else hi = mid; }
    gptr[g] = lo;
}

// agg_e[n][m] = sum of edge_attr (f32) over in-edges of n (constant across convs)
__global__ void k_agge(const float* __restrict__ ea, const int* __restrict__ rp,
                       const int* __restrict__ col_eid, float* __restrict__ agge, int N) {
    int t = blockIdx.x * 256 + threadIdx.x;
    int n = t >> 4, m = t & 15;
    if (n >= N) return;
    float v = 0.f;
    int p1 = rp[n + 1];
    for (int p = rp[n]; p < p1; p++) v += ea[(size_t)col_eid[p] * 16 + m];
    agge[(size_t)n * 16 + m] = v;
}

// ---------------- fused softmax + segment-sum pool (MFMA, two-phase, no z storage) ----------------
// 16 waves/block share one LDS copy of W_out (swizzled into B-fragment order).
// Per 32-node pair-tile: phase 1 computes softmax denominators via MFMA (raw exp,
// no max shift -- |z| << 88 so f32 exp is safe); phase 2 recomputes z bitwise-
// identically and accumulates exp(z)/s into the per-feature accumulator.
__global__ __launch_bounds__(1024) void k_pass(
    const u16* __restrict__ x, const float* __restrict__ Wow, const float* __restrict__ Wob,
    const int* __restrict__ gptr, float* __restrict__ fp, int G, int writeMode)
{
    __shared__ u16 Wsw[64 * 64 * 8];   // [64 frags][64 lanes][8 bf16] = 64 KB
    for (int s = threadIdx.x; s < 4096; s += 1024) {
        int frag = s >> 6, lane = s & 63;
        int ft = frag >> 1, kt = frag & 1;
        int f = ft * 16 + (lane & 15);
        int k = kt * 32 + ((lane >> 4) & 3) * 8;
        const float* wp = Wow + f * 64 + k;      // B[k][f] = W_out[f][k], 8 consecutive k
        u16 o[8];
#pragma unroll
        for (int i = 0; i < 8; i++) o[i] = f2b(wp[i]);
        ((uint4*)Wsw)[s] = *(uint4*)o;
    }
    __syncthreads();
    const int wid = threadIdx.x >> 6, lane = threadIdx.x & 63;
    const int quad = lane >> 4, col = lane & 15;

    // bias for (ft, col), packed bf16 pairs to save VGPRs
    unsigned bpk[16];
#pragma unroll
    for (int i = 0; i < 16; i++) {
        u16 lo = f2b(Wob[(2 * i) * 16 + col]);
        u16 hi = f2b(Wob[(2 * i + 1) * 16 + col]);
        bpk[i] = ((unsigned)lo) | (((unsigned)hi) << 16);
    }

    for (int g = blockIdx.x * 16 + wid; g < G; g += gridDim.x * 16) {
        int gs = gptr[g], ge = gptr[g + 1];
        int cnt = ge - gs;
        float fpacc[32];
#pragma unroll
        for (int t = 0; t < 32; t++) fpacc[t] = 0.f;

        for (int base = gs; base < ge; base += 32) {
            int n0 = base + col, n1 = base + 16 + col;
            bool v0 = n0 < ge, v1 = n1 < ge;
            const uint4* r0 = (const uint4*)(x + (size_t)(v0 ? n0 : gs) * 64);
            const uint4* r1 = (const uint4*)(x + (size_t)(v1 ? n1 : gs) * 64);
            uint4 a0u = r0[quad], a1u = r0[quad + 4];
            uint4 a2u = r1[quad], a3u = r1[quad + 4];
            if (!v0) { a0u.x = a0u.y = a0u.z = a0u.w = 0u; a1u = a0u; }
            if (!v1) { a2u.x = a2u.y = a2u.z = a2u.w = 0u; a3u = a2u; }
            bfx8 a0 = *(bfx8*)&a0u, a1 = *(bfx8*)&a1u;
            bfx8 a2 = *(bfx8*)&a2u, a3 = *(bfx8*)&a3u;

            float s0[4] = {0.f, 0.f, 0.f, 0.f}, s1[4] = {0.f, 0.f, 0.f, 0.f};
#pragma unroll 4
            for (int ft = 0; ft < 32; ft++) {
                float b = (ft & 1) ? bpk_hi(bpk[ft >> 1]) : bpk_lo(bpk[ft >> 1]);
                bfx8 b0 = *(bfx8*)(Wsw + ((ft * 2 + 0) * 64 + lane) * 8);
                bfx8 b1 = *(bfx8*)(Wsw + ((ft * 2 + 1) * 64 + lane) * 8);
                fx4 acc0 = {b, b, b, b}, acc1 = {b, b, b, b};
                acc0 = __builtin_amdgcn_mfma_f32_16x16x32_bf16(a0, b0, acc0, 0, 0, 0);
                acc0 = __builtin_amdgcn_mfma_f32_16x16x32_bf16(a1, b1, acc0, 0, 0, 0);
                acc1 = __builtin_amdgcn_mfma_f32_16x16x32_bf16(a2, b0, acc1, 0, 0, 0);
                acc1 = __builtin_amdgcn_mfma_f32_16x16x32_bf16(a3, b1, acc1, 0, 0, 0);
#pragma unroll
                for (int r = 0; r < 4; r++) {
                    s0[r] += __expf(acc0[r]);
                    s1[r] += __expf(acc1[r]);
                }
            }
            float rinv0[4], rinv1[4];
#pragma unroll
            for (int r = 0; r < 4; r++) {
                float t0 = s0[r], t1 = s1[r];
#pragma unroll
                for (int off = 1; off < 16; off <<= 1) {
                    t0 += __shfl_xor(t0, off, 64);
                    t1 += __shfl_xor(t1, off, 64);
                }
                int row0 = base - gs + quad * 4 + r;       // C-layout: row = quad*4+r
                rinv0[r] = (row0 < cnt) ? __builtin_amdgcn_rcpf(t0) : 0.f;
                rinv1[r] = (row0 + 16 < cnt) ? __builtin_amdgcn_rcpf(t1) : 0.f;
            }
#pragma unroll 4
            for (int ft = 0; ft < 32; ft++) {
                float b = (ft & 1) ? bpk_hi(bpk[ft >> 1]) : bpk_lo(bpk[ft >> 1]);
                bfx8 b0 = *(bfx8*)(Wsw + ((ft * 2 + 0) * 64 + lane) * 8);
                bfx8 b1 = *(bfx8*)(Wsw + ((ft * 2 + 1) * 64 + lane) * 8);
                fx4 acc0 = {b, b, b, b}, acc1 = {b, b, b, b};
                acc0 = __builtin_amdgcn_mfma_f32_16x16x32_bf16(a0, b0, acc0, 0, 0, 0);
                acc0 = __builtin_amdgcn_mfma_f32_16x16x32_bf16(a1, b1, acc0, 0, 0, 0);
                acc1 = __builtin_amdgcn_mfma_f32_16x16x32_bf16(a2, b0, acc1, 0, 0, 0);
                acc1 = __builtin_amdgcn_mfma_f32_16x16x32_bf16(a3, b1, acc1, 0, 0, 0);
                float add = 0.f;
#pragma unroll
                for (int r = 0; r < 4; r++)
                    add += __expf(acc0[r]) * rinv0[r] + __expf(acc1[r]) * rinv1[r];
                fpacc[ft] += add;
            }
        }
#pragma unroll
        for (int ft = 0; ft < 32; ft++) {
            float v = fpacc[ft];
            v += __shfl_xor(v, 16, 64);
            v += __shfl_xor(v, 32, 64);
            if (lane < 16) {
                float* dp = fp + (size_t)g * 512 + ft * 16 + col;
                if (writeMode) *dp = v; else *dp += v;
            }
        }
    }
}

// ---------------- conv part 1: y = x @ W1.T (MFMA, N x 64 x 64) ----------------
__global__ __launch_bounds__(256) void k_gemm(
    const u16* __restrict__ x, const float* __restrict__ Wiw, u16* __restrict__ y, int N)
{
    __shared__ u16 Wsw[8 * 64 * 8];
    for (int s = threadIdx.x; s < 512; s += 256) {
        int frag = s >> 6, lane = s & 63;
        int ft = frag >> 1, kt = frag & 1;
        int f = ft * 16 + (lane & 15);
        int k = kt * 32 + ((lane >> 4) & 3) * 8;
        const float* wp = Wiw + f * 80 + k;      // W1[f][k] = W_in_w[f*80 + k]
        u16 o[8];
#pragma unroll
        for (int i = 0; i < 8; i++) o[i] = f2b(wp[i]);
        ((uint4*)Wsw)[s] = *(uint4*)o;
    }
    __syncthreads();
    const int wid = threadIdx.x >> 6, lane = threadIdx.x & 63;
    const int quad = lane >> 4, col = lane & 15;
    int ntile = N >> 4;
    for (int t = blockIdx.x * 4 + wid; t < ntile; t += gridDim.x * 4) {
        const uint4* rowp = (const uint4*)(x + (size_t)(t * 16 + col) * 64);
        uint4 a0u = rowp[quad], a1u = rowp[quad + 4];
        bfx8 a0 = *(bfx8*)&a0u, a1 = *(bfx8*)&a1u;
#pragma unroll
        for (int ft = 0; ft < 4; ft++) {
            fx4 acc = {0.f, 0.f, 0.f, 0.f};
            bfx8 b0 = *(bfx8*)(Wsw + ((ft * 2 + 0) * 64 + lane) * 8);
            bfx8 b1 = *(bfx8*)(Wsw + ((ft * 2 + 1) * 64 + lane) * 8);
            acc = __builtin_amdgcn_mfma_f32_16x16x32_bf16(a0, b0, acc, 0, 0, 0);
            acc = __builtin_amdgcn_mfma_f32_16x16x32_bf16(a1, b1, acc, 0, 0, 0);
#pragma unroll
            for (int r = 0; r < 4; r++)
                y[(size_t)(t * 16 + quad * 4 + r) * 64 + ft * 16 + col] = f2b(acc[r]);
        }
    }
}

// ---------------- conv part 2: x_out[n] = y[n] + sum_{e->n} y[src] + agg_e[n]@W2.T + b ----------------
__global__ __launch_bounds__(256) void k_gath(
    const u16* __restrict__ y, const float* __restrict__ agge,
    const float* __restrict__ Wiw, const float* __restrict__ Wib,
    const int* __restrict__ rp, const int* __restrict__ col_src,
    u16* __restrict__ xb, int N)
{
    __shared__ float W2t[16 * 64];
    __shared__ float bias[64];
    for (int s = threadIdx.x; s < 1024; s += 256) {
        int m = s >> 6, j = s & 63;
        W2t[s] = Wiw[j * 80 + 64 + m];
    }
    if (threadIdx.x < 64) bias[threadIdx.x] = Wib[threadIdx.x];
    __syncthreads();
    const int wid = threadIdx.x >> 6, lane = threadIdx.x & 63;
    int nw = gridDim.x * 4;
    for (int n = blockIdx.x * 4 + wid; n < N; n += nw) {
        float acc = b2f(y[(size_t)n * 64 + lane]) + bias[lane];   // self loop + bias
        int p1 = rp[n + 1];
        for (int p = rp[n]; p < p1; p++) {
            int s = col_src[p];
            acc += b2f(y[(size_t)s * 64 + lane]);
        }
        const float* ae = agge + (size_t)n * 16;
#pragma unroll
        for (int m = 0; m < 16; m++) acc += ae[m] * W2t[m * 64 + lane];
        xb[(size_t)n * 64 + lane] = f2b(acc);
    }
}

// ---------------- head: sigmoid(lin2(lin1(fp))) — all f32 ----------------
__global__ __launch_bounds__(256) void k_head(
    const float* __restrict__ fp, const float* __restrict__ l1w, const float* __restrict__ l1b,
    const float* __restrict__ l2w, const float* __restrict__ l2b, float* __restrict__ out, int G)
{
    const int wid = threadIdx.x >> 6, lane = threadIdx.x & 63;
    int g = blockIdx.x * 4 + wid;
    if (g >= G) return;
    int j = lane < 50 ? lane : 49;
    float h = 0.f;
    const float4* fv = (const float4*)(fp + (size_t)g * 512);
    const float4* wv = (const float4*)(l1w + (size_t)j * 512);
    for (int q = 0; q < 128; q++) {
        float4 w = wv[q], f = fv[q];
        h += w.x * f.x + w.y * f.y + w.z * f.z + w.w * f.w;
    }
    h += l1b[j];
    float val = (lane < 50) ? h * l2w[lane] : 0.f;
#pragma unroll
    for (int off = 1; off < 64; off <<= 1) val += __shfl_xor(val, off, 64);
    if (lane == 0) {
        float o = val + l2b[0];
        out[g] = 1.f / (1.f + __expf(-o));
    }
}

extern "C" void kernel_launch(void* const* d_in, const int* in_sizes, int n_in,
                              void* d_out, int out_size, void* d_ws, size_t ws_size,
                              hipStream_t stream)
{
    const float* x    = (const float*)d_in[0];
    const float* ea   = (const float*)d_in[1];
    const float* Wiw  = (const float*)d_in[2];
    const float* Wib  = (const float*)d_in[3];
    const float* Wow  = (const float*)d_in[4];
    const float* Wob  = (const float*)d_in[5];
    const float* l1w  = (const float*)d_in[6];
    const float* l1b  = (const float*)d_in[7];
    const float* l2w  = (const float*)d_in[8];
    const float* l2b  = (const float*)d_in[9];
    const int* ei     = (const int*)d_in[10];
    const int* batch  = (const int*)d_in[11];
    float* out = (float*)d_out;

    const int N = in_sizes[0] / 64;
    const int E = in_sizes[10] / 2;
    const int G = 16384;
    const int* src = ei;
    const int* dst = ei + E;

    size_t o = 0;
    auto give = [&](size_t bytes) {
        char* p = (char*)d_ws + o;
        o += (bytes + 255) & ~(size_t)255;
        return (void*)p;
    };
    u16*   x16     = (u16*)  give((size_t)N * 64 * 2);   // bf16 cast of input x
    u16*   xb      = (u16*)  give((size_t)N * 64 * 2);   // conv output (bf16)
    u16*   y       = (u16*)  give((size_t)N * 64 * 2);   // x @ W1.T  (bf16)
    float* agge    = (float*)give((size_t)N * 16 * 4);
    float* fp      = (float*)give((size_t)G * 512 * 4);
    int*   rp      = (int*)  give((size_t)(N + 1) * 4);
    int*   cursor  = (int*)  give((size_t)N * 4);
    int*   col_src = (int*)  give((size_t)E * 4);
    int*   col_eid = (int*)  give((size_t)E * 4);
    int*   bsum    = (int*)  give(4096);
    int*   gptr    = (int*)  give((size_t)(G + 1) * 4);

    // CSR build (inputs identical each call so result identical each launch)
    hipMemsetAsync(rp, 0, (size_t)(N + 1) * 4, stream);
    k_deg<<<(E + 255) / 256, 256, 0, stream>>>(dst, rp, E);
    int nb = (N + SCAN_CH - 1) / SCAN_CH;       // 245 for N=500000 (must be <= 256)
    k_scanA<<<nb, SCAN_T, 0, stream>>>(rp, bsum, N);
    k_scanB<<<1, SCAN_T, 0, stream>>>(bsum, nb);
    k_scanC<<<(N + 256) / 256, 256, 0, stream>>>(bsum, rp, cursor, N, E);
    k_fill<<<(E + 255) / 256, 256, 0, stream>>>(src, dst, cursor, col_src, col_eid, E);
    k_gptr<<<(G + 256) / 256, 256, 0, stream>>>(batch, gptr, N, G);
    k_agge<<<(N * 16 + 255) / 256, 256, 0, stream>>>(ea, rp, col_eid, agge, N);

    // cast input x -> bf16
    k_cast<<<(N * 64 / 8 + 255) / 256, 256, 0, stream>>>(x, x16, N * 64 / 8);

    // pass 0 on input x (writes fp)
    k_pass<<<512, 1024, 0, stream>>>(x16, Wow, Wob, gptr, fp, G, 1);
    const u16* xc = x16;
    for (int d = 0; d < 4; d++) {
        k_gemm<<<1024, 256, 0, stream>>>(xc, Wiw, y, N);
        k_gath<<<2048, 256, 0, stream>>>(y, agge, Wiw, Wib, rp, col_src, xb, N);
        xc = xb;
        k_pass<<<512, 1024, 0, stream>>>(xc, Wow, Wob, gptr, fp, G, 0);
    }
    k_head<<<G / 4, 256, 0, stream>>>(fp, l1w, l1b, l2w, l2b, out, G);
}